// Round 3
// baseline (718.581 us; speedup 1.0000x reference)
//
#include <hip/hip_runtime.h>
#include <hip/hip_bf16.h>
#include <math.h>

#define SCAN_CHUNK 2048

typedef _Float16 half2v __attribute__((ext_vector_type(2)));
typedef _Float16 half8 __attribute__((ext_vector_type(8)));
typedef float floatx4 __attribute__((ext_vector_type(4)));

#if defined(__has_builtin)
#if __has_builtin(__builtin_amdgcn_fdot2)
#define USE_FDOT2 1
#endif
#endif

// ---------------- CSR build ----------------

__global__ void hist_kernel(const int* __restrict__ dst, int* __restrict__ counts, int e) {
    int i = blockIdx.x * blockDim.x + threadIdx.x;
    if (i < e) atomicAdd(&counts[dst[i]], 1);
}

__global__ __launch_bounds__(256) void scan_block_sums(const int* __restrict__ counts,
                                                       int* __restrict__ bsum, int n) {
    __shared__ int sd[256];
    int t = threadIdx.x;
    int base = blockIdx.x * SCAN_CHUNK + t * 8;
    int s = 0;
#pragma unroll
    for (int j = 0; j < 8; ++j) {
        int idx = base + j;
        if (idx < n) s += counts[idx];
    }
    sd[t] = s;
    __syncthreads();
    for (int off = 128; off > 0; off >>= 1) {
        if (t < off) sd[t] += sd[t + off];
        __syncthreads();
    }
    if (t == 0) bsum[blockIdx.x] = sd[0];
}

// single-wave exclusive scan over nb <= 64 block sums
__global__ void scan_wave(int* bsum, int nb) {
    int lane = threadIdx.x;
    int orig = (lane < nb) ? bsum[lane] : 0;
    int v = orig;
    for (int off = 1; off < 64; off <<= 1) {
        int t = __shfl_up(v, off, 64);
        if (lane >= off) v += t;
    }
    if (lane < nb) bsum[lane] = v - orig;  // exclusive
}

__global__ __launch_bounds__(256) void scan_write(const int* __restrict__ counts,
                                                  const int* __restrict__ bsum,
                                                  int* __restrict__ row_ptr,
                                                  int* __restrict__ cursor,
                                                  int n, int total) {
    __shared__ int sd[256];
    int t = threadIdx.x;
    int base = blockIdx.x * SCAN_CHUNK + t * 8;
    int v[8];
    int s = 0;
#pragma unroll
    for (int j = 0; j < 8; ++j) {
        int idx = base + j;
        v[j] = (idx < n) ? counts[idx] : 0;
        s += v[j];
    }
    sd[t] = s;
    __syncthreads();
    for (int off = 1; off < 256; off <<= 1) {
        int tmp = 0;
        if (t >= off) tmp = sd[t - off];
        __syncthreads();
        if (t >= off) sd[t] += tmp;
        __syncthreads();
    }
    int run = bsum[blockIdx.x] + sd[t] - s;
#pragma unroll
    for (int j = 0; j < 8; ++j) {
        int idx = base + j;
        if (idx < n) {
            row_ptr[idx] = run;
            cursor[idx] = run;
            run += v[j];
        }
    }
    if (blockIdx.x == 0 && t == 0) row_ptr[n] = total;
}

// scatter edges into CSR order; record src per slot and slot per edge
__global__ void fill_csr(const int* __restrict__ dst, const int* __restrict__ src,
                         int* cursor, int* __restrict__ srcp,
                         int* __restrict__ pos, int e) {
    int i = blockIdx.x * blockDim.x + threadIdx.x;
    if (i < e) {
        int p = atomicAdd(&cursor[dst[i]], 1);
        srcp[p] = src[i];
        pos[i] = p;
    }
}

// ---------------- mix precompute: mixf[p][h] = sum_m pi[dst,h,m]*vw[e,m] ----------------
// Edge-parallel, writes in CSR slot order so edge_attn reads it coalesced by slot.

__global__ __launch_bounds__(256) void mix_kernel(
    const float* __restrict__ pi, const float* __restrict__ vw,
    const int* __restrict__ dst, const int* __restrict__ pos,
    float* __restrict__ mixf, int e) {
    int i = blockIdx.x * blockDim.x + threadIdx.x;
    if (i >= e) return;
    int d = dst[i];
    int p = pos[i];
    float w0 = vw[3 * i], w1 = vw[3 * i + 1], w2 = vw[3 * i + 2];
    const float4* pp = (const float4*)(pi + (size_t)d * 24);  // 96B, 16B-aligned
    float4 a0 = pp[0], a1 = pp[1], a2 = pp[2], a3 = pp[3], a4 = pp[4], a5 = pp[5];
    float m[8];
    m[0] = fmaf(a0.x, w0, fmaf(a0.y, w1, a0.z * w2));
    m[1] = fmaf(a0.w, w0, fmaf(a1.x, w1, a1.y * w2));
    m[2] = fmaf(a1.z, w0, fmaf(a1.w, w1, a2.x * w2));
    m[3] = fmaf(a2.y, w0, fmaf(a2.z, w1, a2.w * w2));
    m[4] = fmaf(a3.x, w0, fmaf(a3.y, w1, a3.z * w2));
    m[5] = fmaf(a3.w, w0, fmaf(a4.x, w1, a4.y * w2));
    m[6] = fmaf(a4.z, w0, fmaf(a4.w, w1, a5.x * w2));
    m[7] = fmaf(a5.y, w0, fmaf(a5.z, w1, a5.w * w2));
    float4* op = (float4*)(mixf + (size_t)p * 8);
    op[0] = make_float4(m[0], m[1], m[2], m[3]);
    op[1] = make_float4(m[4], m[5], m[6], m[7]);
}

// ---------------- fp16 prep ----------------

__global__ __launch_bounds__(256) void convert_x(const float* __restrict__ x,
                                                 _Float16* __restrict__ xh, int total8) {
    int i = blockIdx.x * blockDim.x + threadIdx.x;
    if (i < total8) {
        const float4* s = (const float4*)x + i * 2;
        float4 a = s[0], b = s[1];
        half8 h;
        h[0] = (_Float16)a.x; h[1] = (_Float16)a.y; h[2] = (_Float16)a.z; h[3] = (_Float16)a.w;
        h[4] = (_Float16)b.x; h[5] = (_Float16)b.y; h[6] = (_Float16)b.z; h[7] = (_Float16)b.w;
        *((half8*)xh + i) = h;
    }
}

// transpose+convert W [k][n] fp32 -> wt [n][k] fp16; blockIdx.x selects matrix
__global__ __launch_bounds__(256) void prep_w(const float* __restrict__ Wq,
                                              const float* __restrict__ Wk,
                                              const float* __restrict__ Wv,
                                              _Float16* __restrict__ wt) {
    const float* W = (blockIdx.x == 0) ? Wq : (blockIdx.x == 1) ? Wk : Wv;
    _Float16* out = wt + (size_t)blockIdx.x * 16384;
    int t = threadIdx.x;
    for (int r = 0; r < 64; ++r) {
        int idx = r * 256 + t;          // idx = k*128 + n
        int k = idx >> 7, nn = idx & 127;
        out[nn * 128 + k] = (_Float16)W[idx];
    }
}

// ---------------- QKV projection: fp16 MFMA ----------------

#define LDP 136  // 128 + 8 halfs pad

__global__ __launch_bounds__(256) void qkv_mfma(
    const _Float16* __restrict__ xh, const _Float16* __restrict__ wt,
    const float* __restrict__ bq, const float* __restrict__ bk,
    const float* __restrict__ bv,
    _Float16* __restrict__ qh, _Float16* __restrict__ kh, _Float16* __restrict__ vh,
    int n) {
    __shared__ __align__(16) _Float16 xs[128 * LDP];
    __shared__ __align__(16) _Float16 ws[128 * LDP];

    int t = threadIdx.x;
    int tile0 = blockIdx.x * 128;
    int sel = blockIdx.y;
    const _Float16* wsel = wt + (size_t)sel * 16384;
    const float* bias = (sel == 0) ? bq : (sel == 1) ? bk : bv;
    _Float16* out = (sel == 0) ? qh : (sel == 1) ? kh : vh;

#pragma unroll
    for (int r = 0; r < 8; ++r) {
        int id = r * 256 + t;
        int row = id >> 4, c8 = id & 15;
        int grow = tile0 + row;
        half8 val = (half8)(_Float16)0;
        if (grow < n) val = *((const half8*)(xh + (size_t)grow * 128) + c8);
        *((half8*)(xs + row * LDP) + c8) = val;
        half8 wv = *((const half8*)(wsel + row * 128) + c8);
        *((half8*)(ws + row * LDP) + c8) = wv;
    }
    __syncthreads();

    int wave = t >> 6, lane = t & 63;
    int wm = (wave & 1) * 64, wn = (wave >> 1) * 64;
    int lrow = lane & 15, quad = lane >> 4;

    floatx4 acc[4][4];
#pragma unroll
    for (int i = 0; i < 4; ++i)
#pragma unroll
        for (int j = 0; j < 4; ++j) acc[i][j] = (floatx4)0.f;

#pragma unroll
    for (int kk = 0; kk < 4; ++kk) {
        int kbase = kk * 32 + quad * 8;
        half8 a[4], b[4];
#pragma unroll
        for (int i = 0; i < 4; ++i)
            a[i] = *(const half8*)(xs + (wm + i * 16 + lrow) * LDP + kbase);
#pragma unroll
        for (int j = 0; j < 4; ++j)
            b[j] = *(const half8*)(ws + (wn + j * 16 + lrow) * LDP + kbase);
#pragma unroll
        for (int i = 0; i < 4; ++i)
#pragma unroll
            for (int j = 0; j < 4; ++j)
                acc[i][j] = __builtin_amdgcn_mfma_f32_16x16x32_f16(a[i], b[j], acc[i][j], 0, 0, 0);
    }

#pragma unroll
    for (int i = 0; i < 4; ++i) {
#pragma unroll
        for (int j = 0; j < 4; ++j) {
            int col = wn + j * 16 + lrow;
            float bv_ = bias[col];
#pragma unroll
            for (int r = 0; r < 4; ++r) {
                int row = wm + i * 16 + quad * 4 + r;
                int grow = tile0 + row;
                if (grow < n) out[(size_t)grow * 128 + col] = (_Float16)(acc[i][j][r] + bv_);
            }
        }
    }
}

// ---------------- Node-centric attention: 16 threads/node, slim state ----------------
// 2 lanes per head (8 elems each): q 4 VGPR, k/v 4 each, acc 8 fp32. Dot via
// 4x fdot2 + shfl_xor(1). mix precomputed per CSR slot (single 4B coalesced
// load). pbuf written in CSR-slot order (contiguous per node). Depth-1 K/V
// prefetch: while computing edge j, K/V for j+1 in flight, meta (src,mix) for
// j+2 loading. 64-thread blocks (4 nodes/wave, 25000 waves) for fine-grain
// load balance.

__global__ __launch_bounds__(64) void edge_attn(
    const _Float16* __restrict__ qh, const _Float16* __restrict__ kh,
    const _Float16* __restrict__ vh, const float* __restrict__ mixf,
    const int* __restrict__ row_ptr, const int* __restrict__ srcp,
    float* __restrict__ node_out, float* __restrict__ invb,
    _Float16* __restrict__ pbuf, int n) {
    int t = threadIdx.x;
    int node = blockIdx.x * 4 + (t >> 4);
    if (node >= n) return;
    int q16 = t & 15;
    int h = q16 >> 1, sub = q16 & 1;
    int off = h * 16 + sub * 8;  // element offset within 128-wide row

    const half8 qv = *(const half8*)(qh + (size_t)node * 128 + off);
    const _Float16* kbase = kh + off;
    const _Float16* vbase = vh + off;

    int beg = row_ptr[node], end = row_ptr[node + 1];

    float l = 0.f;
    float a0 = 0.f, a1 = 0.f, a2 = 0.f, a3 = 0.f;
    float a4 = 0.f, a5 = 0.f, a6 = 0.f, a7 = 0.f;

    // pipeline: current K/V in flight, meta for next slot staged
    half8 kC = (half8)(_Float16)0, vC = (half8)(_Float16)0;
    float mC = 0.f;
    int sN = 0;
    float mN = 0.f;

    if (beg < end) {
        int s0 = srcp[beg];
        mC = mixf[(size_t)beg * 8 + h];
        kC = *(const half8*)(kbase + (size_t)s0 * 128);
        vC = *(const half8*)(vbase + (size_t)s0 * 128);
    }
    if (beg + 1 < end) {
        sN = srcp[beg + 1];
        mN = mixf[(size_t)(beg + 1) * 8 + h];
    }

    for (int j = beg; j < end; ++j) {
        half8 kc = kC, vc = vC;
        float mx = mC;
        // issue next K/V (address from staged meta)
        if (j + 1 < end) {
            kC = *(const half8*)(kbase + (size_t)sN * 128);
            vC = *(const half8*)(vbase + (size_t)sN * 128);
        }
        mC = mN;
        // stage meta for j+2
        if (j + 2 < end) {
            sN = srcp[j + 2];
            mN = mixf[(size_t)(j + 2) * 8 + h];
        }

        float d = 0.f;
#ifdef USE_FDOT2
#pragma unroll
        for (int jj = 0; jj < 4; ++jj) {
            half2v x_, y_;
            x_[0] = qv[2 * jj]; x_[1] = qv[2 * jj + 1];
            y_[0] = kc[2 * jj]; y_[1] = kc[2 * jj + 1];
            d = __builtin_amdgcn_fdot2(x_, y_, d, false);
        }
#else
#pragma unroll
        for (int jj = 0; jj < 8; ++jj) d = fmaf((float)qv[jj], (float)kc[jj], d);
#endif
        d += __shfl_xor(d, 1, 64);  // combine the two half-head partials

        float p = (mx > 0.f) ? mx * __expf(d * 0.25f) : 0.f;
        if (sub == 0) pbuf[(size_t)j * 8 + h] = (_Float16)p;
        l += p;
        a0 = fmaf(p, (float)vc[0], a0);
        a1 = fmaf(p, (float)vc[1], a1);
        a2 = fmaf(p, (float)vc[2], a2);
        a3 = fmaf(p, (float)vc[3], a3);
        a4 = fmaf(p, (float)vc[4], a4);
        a5 = fmaf(p, (float)vc[5], a5);
        a6 = fmaf(p, (float)vc[6], a6);
        a7 = fmaf(p, (float)vc[7], a7);
    }

    float inv = 1.f / fmaxf(l, 1e-8f);
    if (sub == 0) invb[(size_t)node * 8 + h] = inv;

    float4* op = (float4*)(node_out + (size_t)node * 128 + off);
    op[0] = make_float4(a0 * inv, a1 * inv, a2 * inv, a3 * inv);
    op[1] = make_float4(a4 * inv, a5 * inv, a6 * inv, a7 * inv);
}

// ---------------- edge-parallel attention normalize ----------------
// pbuf is in CSR-slot order; pos[i] maps edge -> slot. Output write coalesced.

__global__ __launch_bounds__(256) void attn_norm(
    const _Float16* __restrict__ pbuf, const int* __restrict__ dst,
    const int* __restrict__ pos, const float* __restrict__ invb,
    float* __restrict__ attn_out, int e) {
    int i = blockIdx.x * blockDim.x + threadIdx.x;
    if (i < e) {
        int d = dst[i];
        int p = pos[i];
        half8 pv = *((const half8*)pbuf + p);
        const float4* iv = (const float4*)(invb + (size_t)d * 8);
        float4 i0 = iv[0], i1 = iv[1];
        float4* op = (float4*)(attn_out + (size_t)i * 8);
        op[0] = make_float4((float)pv[0] * i0.x, (float)pv[1] * i0.y,
                            (float)pv[2] * i0.z, (float)pv[3] * i0.w);
        op[1] = make_float4((float)pv[4] * i1.x, (float)pv[5] * i1.y,
                            (float)pv[6] * i1.z, (float)pv[7] * i1.w);
    }
}

// ---------------- launch ----------------

extern "C" void kernel_launch(void* const* d_in, const int* in_sizes, int n_in,
                              void* d_out, int out_size, void* d_ws, size_t ws_size,
                              hipStream_t stream) {
    const float* x  = (const float*)d_in[0];
    const float* pi = (const float*)d_in[1];
    const float* vw = (const float*)d_in[2];
    const float* Wq = (const float*)d_in[3];
    const float* bq = (const float*)d_in[4];
    const float* Wk = (const float*)d_in[5];
    const float* bk = (const float*)d_in[6];
    const float* Wv = (const float*)d_in[7];
    const float* bv = (const float*)d_in[8];
    const int* src  = (const int*)d_in[9];
    const int* dst  = (const int*)d_in[10];

    int n = in_sizes[0] / 128;  // 100000
    int e = in_sizes[9];        // 1600000

    _Float16* xh = (_Float16*)d_ws;
    _Float16* qh = xh + (size_t)n * 128;
    _Float16* kh = qh + (size_t)n * 128;
    _Float16* vh = kh + (size_t)n * 128;
    _Float16* wt = vh + (size_t)n * 128;
    _Float16* pbuf = wt + 3 * 16384;
    float* invb  = (float*)(pbuf + (size_t)e * 8);
    int* counts  = (int*)(invb + (size_t)n * 8);
    int* cursor  = counts + n;
    int* row_ptr = cursor + n;
    int* bsum    = row_ptr + n + 1;
    int* srcp    = bsum + 64;
    int* pos     = srcp + e;

    float* node_out = (float*)d_out;
    float* attn_out = node_out + (size_t)n * 128;
    // mixf scratch lives in the attn output region: written by mix_kernel,
    // consumed by edge_attn, then attn_norm overwrites attn_out.
    float* mixf = attn_out;

    hipMemsetAsync(counts, 0, (size_t)n * sizeof(int), stream);

    int eb = (e + 255) / 256;
    hist_kernel<<<eb, 256, 0, stream>>>(dst, counts, e);

    int nb = (n + SCAN_CHUNK - 1) / SCAN_CHUNK;  // 49
    scan_block_sums<<<nb, 256, 0, stream>>>(counts, bsum, n);
    scan_wave<<<1, 64, 0, stream>>>(bsum, nb);
    scan_write<<<nb, 256, 0, stream>>>(counts, bsum, row_ptr, cursor, n, e);
    fill_csr<<<eb, 256, 0, stream>>>(dst, src, cursor, srcp, pos, e);
    mix_kernel<<<eb, 256, 0, stream>>>(pi, vw, dst, pos, mixf, e);

    int tot8 = (n * 128) / 8;
    convert_x<<<(tot8 + 255) / 256, 256, 0, stream>>>(x, xh, tot8);
    prep_w<<<3, 256, 0, stream>>>(Wq, Wk, Wv, wt);

    int gtiles = (n + 127) / 128;
    qkv_mfma<<<dim3(gtiles, 3), 256, 0, stream>>>(xh, wt, bq, bk, bv, qh, kh, vh, n);

    int gb = (n + 3) / 4;
    edge_attn<<<gb, 64, 0, stream>>>(qh, kh, vh, mixf, row_ptr, srcp,
                                     node_out, invb, pbuf, n);
    attn_norm<<<eb, 256, 0, stream>>>(pbuf, dst, pos, invb, attn_out, e);
}

// Round 4
// 619.327 us; speedup vs baseline: 1.1603x; 1.1603x over previous
//
#include <hip/hip_runtime.h>
#include <hip/hip_bf16.h>
#include <math.h>

#define SCAN_CHUNK 2048

typedef _Float16 half2v __attribute__((ext_vector_type(2)));
typedef _Float16 half8 __attribute__((ext_vector_type(8)));
typedef float floatx4 __attribute__((ext_vector_type(4)));

#if defined(__has_builtin)
#if __has_builtin(__builtin_amdgcn_fdot2)
#define USE_FDOT2 1
#endif
#endif

// ---------------- CSR build ----------------

__global__ void hist_kernel(const int* __restrict__ dst, int* __restrict__ counts, int e) {
    int i = blockIdx.x * blockDim.x + threadIdx.x;
    if (i < e) atomicAdd(&counts[dst[i]], 1);
}

__global__ __launch_bounds__(256) void scan_block_sums(const int* __restrict__ counts,
                                                       int* __restrict__ bsum, int n) {
    __shared__ int sd[256];
    int t = threadIdx.x;
    int base = blockIdx.x * SCAN_CHUNK + t * 8;
    int s = 0;
#pragma unroll
    for (int j = 0; j < 8; ++j) {
        int idx = base + j;
        if (idx < n) s += counts[idx];
    }
    sd[t] = s;
    __syncthreads();
    for (int off = 128; off > 0; off >>= 1) {
        if (t < off) sd[t] += sd[t + off];
        __syncthreads();
    }
    if (t == 0) bsum[blockIdx.x] = sd[0];
}

// single-wave exclusive scan over nb <= 64 block sums
__global__ void scan_wave(int* bsum, int nb) {
    int lane = threadIdx.x;
    int orig = (lane < nb) ? bsum[lane] : 0;
    int v = orig;
    for (int off = 1; off < 64; off <<= 1) {
        int t = __shfl_up(v, off, 64);
        if (lane >= off) v += t;
    }
    if (lane < nb) bsum[lane] = v - orig;  // exclusive
}

__global__ __launch_bounds__(256) void scan_write(const int* __restrict__ counts,
                                                  const int* __restrict__ bsum,
                                                  int* __restrict__ row_ptr,
                                                  int* __restrict__ cursor,
                                                  int n, int total) {
    __shared__ int sd[256];
    int t = threadIdx.x;
    int base = blockIdx.x * SCAN_CHUNK + t * 8;
    int v[8];
    int s = 0;
#pragma unroll
    for (int j = 0; j < 8; ++j) {
        int idx = base + j;
        v[j] = (idx < n) ? counts[idx] : 0;
        s += v[j];
    }
    sd[t] = s;
    __syncthreads();
    for (int off = 1; off < 256; off <<= 1) {
        int tmp = 0;
        if (t >= off) tmp = sd[t - off];
        __syncthreads();
        if (t >= off) sd[t] += tmp;
        __syncthreads();
    }
    int run = bsum[blockIdx.x] + sd[t] - s;
#pragma unroll
    for (int j = 0; j < 8; ++j) {
        int idx = base + j;
        if (idx < n) {
            row_ptr[idx] = run;
            cursor[idx] = run;
            run += v[j];
        }
    }
    if (blockIdx.x == 0 && t == 0) row_ptr[n] = total;
}

// scatter edges into CSR slots as packed 16B records:
// {src, edge_id, (w0|w1 as half2), w2 as half}. One broadcast int4 load per
// edge in edge_attn; edge id lets pbuf stay edge-indexed (coalesced attn_norm).
__global__ void fill_csr(const int* __restrict__ dst, const int* __restrict__ src,
                         const float* __restrict__ vw, int* cursor,
                         int4* __restrict__ recs, int e) {
    int i = blockIdx.x * blockDim.x + threadIdx.x;
    if (i < e) {
        int p = atomicAdd(&cursor[dst[i]], 1);
        float w0 = vw[3 * i], w1 = vw[3 * i + 1], w2 = vw[3 * i + 2];
        unsigned u0 = (unsigned)__builtin_bit_cast(unsigned short, (_Float16)w0);
        unsigned u1 = (unsigned)__builtin_bit_cast(unsigned short, (_Float16)w1);
        unsigned u2 = (unsigned)__builtin_bit_cast(unsigned short, (_Float16)w2);
        int4 r;
        r.x = src[i];
        r.y = i;
        r.z = (int)(u0 | (u1 << 16));
        r.w = (int)u2;
        recs[p] = r;
    }
}

// ---------------- fp16 prep ----------------

__global__ __launch_bounds__(256) void convert_x(const float* __restrict__ x,
                                                 _Float16* __restrict__ xh, int total8) {
    int i = blockIdx.x * blockDim.x + threadIdx.x;
    if (i < total8) {
        const float4* s = (const float4*)x + i * 2;
        float4 a = s[0], b = s[1];
        half8 h;
        h[0] = (_Float16)a.x; h[1] = (_Float16)a.y; h[2] = (_Float16)a.z; h[3] = (_Float16)a.w;
        h[4] = (_Float16)b.x; h[5] = (_Float16)b.y; h[6] = (_Float16)b.z; h[7] = (_Float16)b.w;
        *((half8*)xh + i) = h;
    }
}

// transpose+convert W [k][n] fp32 -> wt [n][k] fp16; blockIdx.x selects matrix
__global__ __launch_bounds__(256) void prep_w(const float* __restrict__ Wq,
                                              const float* __restrict__ Wk,
                                              const float* __restrict__ Wv,
                                              _Float16* __restrict__ wt) {
    const float* W = (blockIdx.x == 0) ? Wq : (blockIdx.x == 1) ? Wk : Wv;
    _Float16* out = wt + (size_t)blockIdx.x * 16384;
    int t = threadIdx.x;
    for (int r = 0; r < 64; ++r) {
        int idx = r * 256 + t;          // idx = k*128 + n
        int k = idx >> 7, nn = idx & 127;
        out[nn * 128 + k] = (_Float16)W[idx];
    }
}

// ---------------- QKV projection: fp16 MFMA ----------------

#define LDP 136  // 128 + 8 halfs pad

__global__ __launch_bounds__(256) void qkv_mfma(
    const _Float16* __restrict__ xh, const _Float16* __restrict__ wt,
    const float* __restrict__ bq, const float* __restrict__ bk,
    const float* __restrict__ bv,
    _Float16* __restrict__ qh, _Float16* __restrict__ kh, _Float16* __restrict__ vh,
    int n) {
    __shared__ __align__(16) _Float16 xs[128 * LDP];
    __shared__ __align__(16) _Float16 ws[128 * LDP];

    int t = threadIdx.x;
    int tile0 = blockIdx.x * 128;
    int sel = blockIdx.y;
    const _Float16* wsel = wt + (size_t)sel * 16384;
    const float* bias = (sel == 0) ? bq : (sel == 1) ? bk : bv;
    _Float16* out = (sel == 0) ? qh : (sel == 1) ? kh : vh;

#pragma unroll
    for (int r = 0; r < 8; ++r) {
        int id = r * 256 + t;
        int row = id >> 4, c8 = id & 15;
        int grow = tile0 + row;
        half8 val = (half8)(_Float16)0;
        if (grow < n) val = *((const half8*)(xh + (size_t)grow * 128) + c8);
        *((half8*)(xs + row * LDP) + c8) = val;
        half8 wv = *((const half8*)(wsel + row * 128) + c8);
        *((half8*)(ws + row * LDP) + c8) = wv;
    }
    __syncthreads();

    int wave = t >> 6, lane = t & 63;
    int wm = (wave & 1) * 64, wn = (wave >> 1) * 64;
    int lrow = lane & 15, quad = lane >> 4;

    floatx4 acc[4][4];
#pragma unroll
    for (int i = 0; i < 4; ++i)
#pragma unroll
        for (int j = 0; j < 4; ++j) acc[i][j] = (floatx4)0.f;

#pragma unroll
    for (int kk = 0; kk < 4; ++kk) {
        int kbase = kk * 32 + quad * 8;
        half8 a[4], b[4];
#pragma unroll
        for (int i = 0; i < 4; ++i)
            a[i] = *(const half8*)(xs + (wm + i * 16 + lrow) * LDP + kbase);
#pragma unroll
        for (int j = 0; j < 4; ++j)
            b[j] = *(const half8*)(ws + (wn + j * 16 + lrow) * LDP + kbase);
#pragma unroll
        for (int i = 0; i < 4; ++i)
#pragma unroll
            for (int j = 0; j < 4; ++j)
                acc[i][j] = __builtin_amdgcn_mfma_f32_16x16x32_f16(a[i], b[j], acc[i][j], 0, 0, 0);
    }

#pragma unroll
    for (int i = 0; i < 4; ++i) {
#pragma unroll
        for (int j = 0; j < 4; ++j) {
            int col = wn + j * 16 + lrow;
            float bv_ = bias[col];
#pragma unroll
            for (int r = 0; r < 4; ++r) {
                int row = wm + i * 16 + quad * 4 + r;
                int grow = tile0 + row;
                if (grow < n) out[(size_t)grow * 128 + col] = (_Float16)(acc[i][j][r] + bv_);
            }
        }
    }
}

// ---------------- Node-centric attention: 16 thr/node, depth-2 pipeline ----------------
// 2 lanes per head (8 elems each): q 4 VGPR, k/v 4 each, acc 8 fp32. Dot via
// 4x fdot2 + shfl_xor(1). mix = 3 FMA against per-head pi regs, weights from
// the packed slot record (one broadcast int4/edge). pbuf edge-indexed.
// 4 named K/V slots, two alternating bodies: computing (j,j+1) while K/V for
// (j+2,j+3) is in flight and meta for (j+4,j+5) is staging. 64-thread blocks
// (4 nodes/wave) for fine-grain balance; launch_bounds caps VGPR at 6 waves/EU.

#define STAGE_META(S, idx)                                                    \
    {                                                                         \
        s##S = 0; e##S = 0; m##S = 0.f;                                       \
        if ((idx) < end) {                                                    \
            int4 r_ = recs[(idx)];                                            \
            s##S = r_.x; e##S = r_.y;                                         \
            half2v w01_ = __builtin_bit_cast(half2v, r_.z);                   \
            _Float16 w2_ =                                                    \
                __builtin_bit_cast(_Float16, (unsigned short)(unsigned)r_.w); \
            m##S = fmaf(p0, (float)w01_[0],                                   \
                        fmaf(p1, (float)w01_[1], p2 * (float)w2_));           \
        }                                                                     \
    }

#define ISSUE_KV(S, idx)                                                      \
    {                                                                         \
        k##S = (half8)(_Float16)0; v##S = (half8)(_Float16)0;                 \
        if ((idx) < end) {                                                    \
            k##S = *(const half8*)(kbase + (size_t)s##S * 128);               \
            v##S = *(const half8*)(vbase + (size_t)s##S * 128);               \
        }                                                                     \
    }

#ifdef USE_FDOT2
#define DOT8(dres, kS)                                                        \
    {                                                                         \
        _Pragma("unroll")                                                     \
        for (int jj_ = 0; jj_ < 4; ++jj_) {                                   \
            half2v x_, y_;                                                    \
            x_[0] = qv[2 * jj_]; x_[1] = qv[2 * jj_ + 1];                     \
            y_[0] = kS[2 * jj_]; y_[1] = kS[2 * jj_ + 1];                     \
            dres = __builtin_amdgcn_fdot2(x_, y_, dres, false);               \
        }                                                                     \
    }
#else
#define DOT8(dres, kS)                                                        \
    {                                                                         \
        _Pragma("unroll")                                                     \
        for (int jj_ = 0; jj_ < 8; ++jj_)                                     \
            dres = fmaf((float)qv[jj_], (float)kS[jj_], dres);                \
    }
#endif

#define COMPUTE(S, mx, ev, validc)                                            \
    {                                                                         \
        float d_ = 0.f;                                                       \
        DOT8(d_, k##S);                                                       \
        d_ += __shfl_xor(d_, 1, 64);                                          \
        float p_ = ((mx) > 0.f) ? (mx)*__expf(d_ * 0.25f) : 0.f;              \
        if (sub == 0 && (validc)) pbuf[(size_t)(ev)*8 + h] = (_Float16)p_;    \
        l += p_;                                                              \
        a0 = fmaf(p_, (float)v##S[0], a0);                                    \
        a1 = fmaf(p_, (float)v##S[1], a1);                                    \
        a2 = fmaf(p_, (float)v##S[2], a2);                                    \
        a3 = fmaf(p_, (float)v##S[3], a3);                                    \
        a4 = fmaf(p_, (float)v##S[4], a4);                                    \
        a5 = fmaf(p_, (float)v##S[5], a5);                                    \
        a6 = fmaf(p_, (float)v##S[6], a6);                                    \
        a7 = fmaf(p_, (float)v##S[7], a7);                                    \
    }

// computes (jj, jj+1) from S0,S1; issues K/V for (jj+2,jj+3) into S2,S3;
// stages meta for (jj+4,jj+5) into the S0,S1 meta slots for the body after next.
#define BODY(S0, S1, S2, S3, jj)                                              \
    {                                                                         \
        ISSUE_KV(S2, (jj) + 2);                                               \
        ISSUE_KV(S3, (jj) + 3);                                               \
        float mx0_ = m##S0, mx1_ = m##S1;                                     \
        int ev0_ = e##S0, ev1_ = e##S1;                                       \
        STAGE_META(S0, (jj) + 4);                                             \
        STAGE_META(S1, (jj) + 5);                                             \
        COMPUTE(S0, mx0_, ev0_, true);                                        \
        COMPUTE(S1, mx1_, ev1_, (jj) + 1 < end);                              \
    }

__global__ __launch_bounds__(64, 6) void edge_attn(
    const _Float16* __restrict__ qh, const _Float16* __restrict__ kh,
    const _Float16* __restrict__ vh, const float* __restrict__ pi,
    const int* __restrict__ row_ptr, const int4* __restrict__ recs,
    float* __restrict__ node_out, float* __restrict__ invb,
    _Float16* __restrict__ pbuf, int n) {
    int t = threadIdx.x;
    int node = blockIdx.x * 4 + (t >> 4);
    if (node >= n) return;
    int q16 = t & 15;
    int h = q16 >> 1, sub = q16 & 1;
    int off = h * 16 + sub * 8;  // element offset within 128-wide row

    const half8 qv = *(const half8*)(qh + (size_t)node * 128 + off);
    const _Float16* kbase = kh + off;
    const _Float16* vbase = vh + off;

    float p0 = pi[node * 24 + h * 3 + 0];
    float p1 = pi[node * 24 + h * 3 + 1];
    float p2 = pi[node * 24 + h * 3 + 2];
    int beg = row_ptr[node], end = row_ptr[node + 1];

    float l = 0.f;
    float a0 = 0.f, a1 = 0.f, a2 = 0.f, a3 = 0.f;
    float a4 = 0.f, a5 = 0.f, a6 = 0.f, a7 = 0.f;

    int sA, eA, sB, eB, sC, eC, sD, eD;
    float mA, mB, mC, mD;
    half8 kA, vA, kB, vB, kC, vC, kD, vD;

    STAGE_META(A, beg);
    STAGE_META(B, beg + 1);
    STAGE_META(C, beg + 2);
    STAGE_META(D, beg + 3);
    ISSUE_KV(A, beg);
    ISSUE_KV(B, beg + 1);

    for (int j = beg; j < end;) {
        BODY(A, B, C, D, j);
        j += 2;
        if (j >= end) break;
        BODY(C, D, A, B, j);
        j += 2;
    }

    float inv = 1.f / fmaxf(l, 1e-8f);
    if (sub == 0) invb[(size_t)node * 8 + h] = inv;

    float4* op = (float4*)(node_out + (size_t)node * 128 + off);
    op[0] = make_float4(a0 * inv, a1 * inv, a2 * inv, a3 * inv);
    op[1] = make_float4(a4 * inv, a5 * inv, a6 * inv, a7 * inv);
}

// ---------------- edge-parallel attention normalize (coalesced) ----------------

__global__ __launch_bounds__(256) void attn_norm(
    const _Float16* __restrict__ pbuf, const int* __restrict__ dst,
    const float* __restrict__ invb, float* __restrict__ attn_out, int e) {
    int i = blockIdx.x * blockDim.x + threadIdx.x;
    if (i < e) {
        int d = dst[i];
        half8 p = *((const half8*)pbuf + i);
        const float4* iv = (const float4*)(invb + (size_t)d * 8);
        float4 i0 = iv[0], i1 = iv[1];
        float4* op = (float4*)(attn_out + (size_t)i * 8);
        op[0] = make_float4((float)p[0] * i0.x, (float)p[1] * i0.y,
                            (float)p[2] * i0.z, (float)p[3] * i0.w);
        op[1] = make_float4((float)p[4] * i1.x, (float)p[5] * i1.y,
                            (float)p[6] * i1.z, (float)p[7] * i1.w);
    }
}

// ---------------- launch ----------------

extern "C" void kernel_launch(void* const* d_in, const int* in_sizes, int n_in,
                              void* d_out, int out_size, void* d_ws, size_t ws_size,
                              hipStream_t stream) {
    const float* x  = (const float*)d_in[0];
    const float* pi = (const float*)d_in[1];
    const float* vw = (const float*)d_in[2];
    const float* Wq = (const float*)d_in[3];
    const float* bq = (const float*)d_in[4];
    const float* Wk = (const float*)d_in[5];
    const float* bk = (const float*)d_in[6];
    const float* Wv = (const float*)d_in[7];
    const float* bv = (const float*)d_in[8];
    const int* src  = (const int*)d_in[9];
    const int* dst  = (const int*)d_in[10];

    int n = in_sizes[0] / 128;  // 100000
    int e = in_sizes[9];        // 1600000

    _Float16* xh = (_Float16*)d_ws;
    _Float16* qh = xh + (size_t)n * 128;
    _Float16* kh = qh + (size_t)n * 128;
    _Float16* vh = kh + (size_t)n * 128;
    _Float16* wt = vh + (size_t)n * 128;
    _Float16* pbuf = wt + 3 * 16384;
    float* invb  = (float*)(pbuf + (size_t)e * 8);
    int* counts  = (int*)(invb + (size_t)n * 8);
    int* cursor  = counts + n;
    int* row_ptr = cursor + n;
    int* bsum    = row_ptr + n + 1;

    float* node_out = (float*)d_out;
    float* attn_out = node_out + (size_t)n * 128;
    // recs scratch (16B/edge = 25.6MB) lives in the 51.2MB attn output region:
    // written by fill_csr, consumed by edge_attn, overwritten by attn_norm.
    int4* recs = (int4*)attn_out;

    hipMemsetAsync(counts, 0, (size_t)n * sizeof(int), stream);

    int eb = (e + 255) / 256;
    hist_kernel<<<eb, 256, 0, stream>>>(dst, counts, e);

    int nb = (n + SCAN_CHUNK - 1) / SCAN_CHUNK;  // 49
    scan_block_sums<<<nb, 256, 0, stream>>>(counts, bsum, n);
    scan_wave<<<1, 64, 0, stream>>>(bsum, nb);
    scan_write<<<nb, 256, 0, stream>>>(counts, bsum, row_ptr, cursor, n, e);
    fill_csr<<<eb, 256, 0, stream>>>(dst, src, vw, cursor, recs, e);

    int tot8 = (n * 128) / 8;
    convert_x<<<(tot8 + 255) / 256, 256, 0, stream>>>(x, xh, tot8);
    prep_w<<<3, 256, 0, stream>>>(Wq, Wk, Wv, wt);

    int gtiles = (n + 127) / 128;
    qkv_mfma<<<dim3(gtiles, 3), 256, 0, stream>>>(xh, wt, bq, bk, bv, qh, kh, vh, n);

    int gb = (n + 3) / 4;
    edge_attn<<<gb, 64, 0, stream>>>(qh, kh, vh, pi, row_ptr, recs,
                                     node_out, invb, pbuf, n);
    attn_norm<<<eb, 256, 0, stream>>>(pbuf, dst, invb, attn_out, e);
}

// Round 5
// 619.111 us; speedup vs baseline: 1.1607x; 1.0003x over previous
//
#include <hip/hip_runtime.h>
#include <hip/hip_bf16.h>
#include <math.h>

#define SCAN_CHUNK 2048

typedef _Float16 half2v __attribute__((ext_vector_type(2)));
typedef _Float16 half8 __attribute__((ext_vector_type(8)));
typedef float floatx4 __attribute__((ext_vector_type(4)));

#if defined(__has_builtin)
#if __has_builtin(__builtin_amdgcn_fdot2)
#define USE_FDOT2 1
#endif
#endif

// ---------------- CSR build ----------------

__global__ void hist_kernel(const int* __restrict__ dst, int* __restrict__ counts, int e) {
    int i = blockIdx.x * blockDim.x + threadIdx.x;
    if (i < e) atomicAdd(&counts[dst[i]], 1);
}

__global__ __launch_bounds__(256) void scan_block_sums(const int* __restrict__ counts,
                                                       int* __restrict__ bsum, int n) {
    __shared__ int sd[256];
    int t = threadIdx.x;
    int base = blockIdx.x * SCAN_CHUNK + t * 8;
    int s = 0;
#pragma unroll
    for (int j = 0; j < 8; ++j) {
        int idx = base + j;
        if (idx < n) s += counts[idx];
    }
    sd[t] = s;
    __syncthreads();
    for (int off = 128; off > 0; off >>= 1) {
        if (t < off) sd[t] += sd[t + off];
        __syncthreads();
    }
    if (t == 0) bsum[blockIdx.x] = sd[0];
}

// single-wave exclusive scan over nb <= 64 block sums
__global__ void scan_wave(int* bsum, int nb) {
    int lane = threadIdx.x;
    int orig = (lane < nb) ? bsum[lane] : 0;
    int v = orig;
    for (int off = 1; off < 64; off <<= 1) {
        int t = __shfl_up(v, off, 64);
        if (lane >= off) v += t;
    }
    if (lane < nb) bsum[lane] = v - orig;  // exclusive
}

__global__ __launch_bounds__(256) void scan_write(const int* __restrict__ counts,
                                                  const int* __restrict__ bsum,
                                                  int* __restrict__ row_ptr,
                                                  int* __restrict__ cursor,
                                                  int n, int total) {
    __shared__ int sd[256];
    int t = threadIdx.x;
    int base = blockIdx.x * SCAN_CHUNK + t * 8;
    int v[8];
    int s = 0;
#pragma unroll
    for (int j = 0; j < 8; ++j) {
        int idx = base + j;
        v[j] = (idx < n) ? counts[idx] : 0;
        s += v[j];
    }
    sd[t] = s;
    __syncthreads();
    for (int off = 1; off < 256; off <<= 1) {
        int tmp = 0;
        if (t >= off) tmp = sd[t - off];
        __syncthreads();
        if (t >= off) sd[t] += tmp;
        __syncthreads();
    }
    int run = bsum[blockIdx.x] + sd[t] - s;
#pragma unroll
    for (int j = 0; j < 8; ++j) {
        int idx = base + j;
        if (idx < n) {
            row_ptr[idx] = run;
            cursor[idx] = run;
            run += v[j];
        }
    }
    if (blockIdx.x == 0 && t == 0) row_ptr[n] = total;
}

// scatter edges into CSR slots as packed 16B records {src, w2, (w0|w1)}.
// pos[i] = slot of edge i (coalesced write) lets attn_norm gather slot-ordered
// pbuf. Slot-ordered pbuf keeps edge_attn's p-writes contiguous per node
// (round-4's edge-indexed scatter cost +33MB WRITE / +48MB FETCH there).
__global__ void fill_csr(const int* __restrict__ dst, const int* __restrict__ src,
                         const float* __restrict__ vw, int* cursor,
                         int4* __restrict__ recs, int* __restrict__ pos, int e) {
    int i = blockIdx.x * blockDim.x + threadIdx.x;
    if (i < e) {
        int p = atomicAdd(&cursor[dst[i]], 1);
        float w0 = vw[3 * i], w1 = vw[3 * i + 1], w2 = vw[3 * i + 2];
        unsigned u0 = (unsigned)__builtin_bit_cast(unsigned short, (_Float16)w0);
        unsigned u1 = (unsigned)__builtin_bit_cast(unsigned short, (_Float16)w1);
        unsigned u2 = (unsigned)__builtin_bit_cast(unsigned short, (_Float16)w2);
        int4 r;
        r.x = src[i];
        r.y = (int)u2;
        r.z = (int)(u0 | (u1 << 16));
        r.w = 0;
        recs[p] = r;
        pos[i] = p;
    }
}

// ---------------- fp16 prep ----------------

__global__ __launch_bounds__(256) void convert_x(const float* __restrict__ x,
                                                 _Float16* __restrict__ xh, int total8) {
    int i = blockIdx.x * blockDim.x + threadIdx.x;
    if (i < total8) {
        const float4* s = (const float4*)x + i * 2;
        float4 a = s[0], b = s[1];
        half8 h;
        h[0] = (_Float16)a.x; h[1] = (_Float16)a.y; h[2] = (_Float16)a.z; h[3] = (_Float16)a.w;
        h[4] = (_Float16)b.x; h[5] = (_Float16)b.y; h[6] = (_Float16)b.z; h[7] = (_Float16)b.w;
        *((half8*)xh + i) = h;
    }
}

// transpose+convert W [k][n] fp32 -> wt [n][k] fp16; blockIdx.x selects matrix
__global__ __launch_bounds__(256) void prep_w(const float* __restrict__ Wq,
                                              const float* __restrict__ Wk,
                                              const float* __restrict__ Wv,
                                              _Float16* __restrict__ wt) {
    const float* W = (blockIdx.x == 0) ? Wq : (blockIdx.x == 1) ? Wk : Wv;
    _Float16* out = wt + (size_t)blockIdx.x * 16384;
    int t = threadIdx.x;
    for (int r = 0; r < 64; ++r) {
        int idx = r * 256 + t;          // idx = k*128 + n
        int k = idx >> 7, nn = idx & 127;
        out[nn * 128 + k] = (_Float16)W[idx];
    }
}

// ---------------- QKV projection: fp16 MFMA ----------------

#define LDP 136  // 128 + 8 halfs pad

__global__ __launch_bounds__(256) void qkv_mfma(
    const _Float16* __restrict__ xh, const _Float16* __restrict__ wt,
    const float* __restrict__ bq, const float* __restrict__ bk,
    const float* __restrict__ bv,
    _Float16* __restrict__ qh, _Float16* __restrict__ kh, _Float16* __restrict__ vh,
    int n) {
    __shared__ __align__(16) _Float16 xs[128 * LDP];
    __shared__ __align__(16) _Float16 ws[128 * LDP];

    int t = threadIdx.x;
    int tile0 = blockIdx.x * 128;
    int sel = blockIdx.y;
    const _Float16* wsel = wt + (size_t)sel * 16384;
    const float* bias = (sel == 0) ? bq : (sel == 1) ? bk : bv;
    _Float16* out = (sel == 0) ? qh : (sel == 1) ? kh : vh;

#pragma unroll
    for (int r = 0; r < 8; ++r) {
        int id = r * 256 + t;
        int row = id >> 4, c8 = id & 15;
        int grow = tile0 + row;
        half8 val = (half8)(_Float16)0;
        if (grow < n) val = *((const half8*)(xh + (size_t)grow * 128) + c8);
        *((half8*)(xs + row * LDP) + c8) = val;
        half8 wv = *((const half8*)(wsel + row * 128) + c8);
        *((half8*)(ws + row * LDP) + c8) = wv;
    }
    __syncthreads();

    int wave = t >> 6, lane = t & 63;
    int wm = (wave & 1) * 64, wn = (wave >> 1) * 64;
    int lrow = lane & 15, quad = lane >> 4;

    floatx4 acc[4][4];
#pragma unroll
    for (int i = 0; i < 4; ++i)
#pragma unroll
        for (int j = 0; j < 4; ++j) acc[i][j] = (floatx4)0.f;

#pragma unroll
    for (int kk = 0; kk < 4; ++kk) {
        int kbase = kk * 32 + quad * 8;
        half8 a[4], b[4];
#pragma unroll
        for (int i = 0; i < 4; ++i)
            a[i] = *(const half8*)(xs + (wm + i * 16 + lrow) * LDP + kbase);
#pragma unroll
        for (int j = 0; j < 4; ++j)
            b[j] = *(const half8*)(ws + (wn + j * 16 + lrow) * LDP + kbase);
#pragma unroll
        for (int i = 0; i < 4; ++i)
#pragma unroll
            for (int j = 0; j < 4; ++j)
                acc[i][j] = __builtin_amdgcn_mfma_f32_16x16x32_f16(a[i], b[j], acc[i][j], 0, 0, 0);
    }

#pragma unroll
    for (int i = 0; i < 4; ++i) {
#pragma unroll
        for (int j = 0; j < 4; ++j) {
            int col = wn + j * 16 + lrow;
            float bv_ = bias[col];
#pragma unroll
            for (int r = 0; r < 4; ++r) {
                int row = wm + i * 16 + quad * 4 + r;
                int grow = tile0 + row;
                if (grow < n) out[(size_t)grow * 128 + col] = (_Float16)(acc[i][j][r] + bv_);
            }
        }
    }
}

// ---------------- Node-centric attention: 16 thr/node, depth-2 pipeline ----------------
// 2 lanes per head (8 elems each): q 4 VGPR, k/v 4 each, acc 8 fp32. Dot via
// 4x fdot2 + shfl_xor(1). mix = 3 FMA against per-head pi regs, weights from
// the packed slot record (one broadcast int4/edge). pbuf SLOT-indexed
// (contiguous per node -> coalesced writes; attn_norm gathers via pos[]).
// 4 named K/V slots, two alternating bodies: computing (j,j+1) while K/V for
// (j+2,j+3) is in flight and meta for (j+4,j+5) is staging. 64-thread blocks
// (4 nodes/wave) for fine-grain balance; launch_bounds keeps >=6 waves/EU.

#define STAGE_META(S, idx)                                                    \
    {                                                                         \
        s##S = 0; m##S = 0.f;                                                 \
        if ((idx) < end) {                                                    \
            int4 r_ = recs[(idx)];                                            \
            s##S = r_.x;                                                      \
            half2v w01_ = __builtin_bit_cast(half2v, r_.z);                   \
            _Float16 w2_ =                                                    \
                __builtin_bit_cast(_Float16, (unsigned short)(unsigned)r_.y); \
            m##S = fmaf(p0, (float)w01_[0],                                   \
                        fmaf(p1, (float)w01_[1], p2 * (float)w2_));           \
        }                                                                     \
    }

#define ISSUE_KV(S, idx)                                                      \
    {                                                                         \
        k##S = (half8)(_Float16)0; v##S = (half8)(_Float16)0;                 \
        if ((idx) < end) {                                                    \
            k##S = *(const half8*)(kbase + (size_t)s##S * 128);               \
            v##S = *(const half8*)(vbase + (size_t)s##S * 128);               \
        }                                                                     \
    }

#ifdef USE_FDOT2
#define DOT8(dres, kS)                                                        \
    {                                                                         \
        _Pragma("unroll")                                                     \
        for (int jj_ = 0; jj_ < 4; ++jj_) {                                   \
            half2v x_, y_;                                                    \
            x_[0] = qv[2 * jj_]; x_[1] = qv[2 * jj_ + 1];                     \
            y_[0] = kS[2 * jj_]; y_[1] = kS[2 * jj_ + 1];                     \
            dres = __builtin_amdgcn_fdot2(x_, y_, dres, false);               \
        }                                                                     \
    }
#else
#define DOT8(dres, kS)                                                        \
    {                                                                         \
        _Pragma("unroll")                                                     \
        for (int jj_ = 0; jj_ < 8; ++jj_)                                     \
            dres = fmaf((float)qv[jj_], (float)kS[jj_], dres);                \
    }
#endif

#define COMPUTE(S, mx, slot, validc)                                          \
    {                                                                         \
        float d_ = 0.f;                                                       \
        DOT8(d_, k##S);                                                       \
        d_ += __shfl_xor(d_, 1, 64);                                          \
        float p_ = ((mx) > 0.f) ? (mx)*__expf(d_ * 0.25f) : 0.f;              \
        if (sub == 0 && (validc)) pbuf[(size_t)(slot)*8 + h] = (_Float16)p_;  \
        l += p_;                                                              \
        a0 = fmaf(p_, (float)v##S[0], a0);                                    \
        a1 = fmaf(p_, (float)v##S[1], a1);                                    \
        a2 = fmaf(p_, (float)v##S[2], a2);                                    \
        a3 = fmaf(p_, (float)v##S[3], a3);                                    \
        a4 = fmaf(p_, (float)v##S[4], a4);                                    \
        a5 = fmaf(p_, (float)v##S[5], a5);                                    \
        a6 = fmaf(p_, (float)v##S[6], a6);                                    \
        a7 = fmaf(p_, (float)v##S[7], a7);                                    \
    }

// computes (jj, jj+1) from S0,S1; issues K/V for (jj+2,jj+3) into S2,S3;
// stages meta for (jj+4,jj+5) into the S0,S1 meta slots for the body after next.
#define BODY(S0, S1, S2, S3, jj)                                              \
    {                                                                         \
        ISSUE_KV(S2, (jj) + 2);                                               \
        ISSUE_KV(S3, (jj) + 3);                                               \
        float mx0_ = m##S0, mx1_ = m##S1;                                     \
        STAGE_META(S0, (jj) + 4);                                             \
        STAGE_META(S1, (jj) + 5);                                             \
        COMPUTE(S0, mx0_, (jj), true);                                        \
        COMPUTE(S1, mx1_, (jj) + 1, (jj) + 1 < end);                          \
    }

__global__ __launch_bounds__(64, 6) void edge_attn(
    const _Float16* __restrict__ qh, const _Float16* __restrict__ kh,
    const _Float16* __restrict__ vh, const float* __restrict__ pi,
    const int* __restrict__ row_ptr, const int4* __restrict__ recs,
    float* __restrict__ node_out, float* __restrict__ invb,
    _Float16* __restrict__ pbuf, int n) {
    int t = threadIdx.x;
    int node = blockIdx.x * 4 + (t >> 4);
    if (node >= n) return;
    int q16 = t & 15;
    int h = q16 >> 1, sub = q16 & 1;
    int off = h * 16 + sub * 8;  // element offset within 128-wide row

    const half8 qv = *(const half8*)(qh + (size_t)node * 128 + off);
    const _Float16* kbase = kh + off;
    const _Float16* vbase = vh + off;

    float p0 = pi[node * 24 + h * 3 + 0];
    float p1 = pi[node * 24 + h * 3 + 1];
    float p2 = pi[node * 24 + h * 3 + 2];
    int beg = row_ptr[node], end = row_ptr[node + 1];

    float l = 0.f;
    float a0 = 0.f, a1 = 0.f, a2 = 0.f, a3 = 0.f;
    float a4 = 0.f, a5 = 0.f, a6 = 0.f, a7 = 0.f;

    int sA, sB, sC, sD;
    float mA, mB, mC, mD;
    half8 kA, vA, kB, vB, kC, vC, kD, vD;

    STAGE_META(A, beg);
    STAGE_META(B, beg + 1);
    STAGE_META(C, beg + 2);
    STAGE_META(D, beg + 3);
    ISSUE_KV(A, beg);
    ISSUE_KV(B, beg + 1);

    for (int j = beg; j < end;) {
        BODY(A, B, C, D, j);
        j += 2;
        if (j >= end) break;
        BODY(C, D, A, B, j);
        j += 2;
    }

    float inv = 1.f / fmaxf(l, 1e-8f);
    if (sub == 0) invb[(size_t)node * 8 + h] = inv;

    float4* op = (float4*)(node_out + (size_t)node * 128 + off);
    op[0] = make_float4(a0 * inv, a1 * inv, a2 * inv, a3 * inv);
    op[1] = make_float4(a4 * inv, a5 * inv, a6 * inv, a7 * inv);
}

// ---------------- edge-parallel attention normalize ----------------
// pbuf is slot-ordered; pos[i] maps edge -> slot (coalesced 4B read). pbuf
// gather is 16B from an L2/L3-resident 25.6MB buffer. Output write coalesced.

__global__ __launch_bounds__(256) void attn_norm(
    const _Float16* __restrict__ pbuf, const int* __restrict__ dst,
    const int* __restrict__ pos, const float* __restrict__ invb,
    float* __restrict__ attn_out, int e) {
    int i = blockIdx.x * blockDim.x + threadIdx.x;
    if (i < e) {
        int d = dst[i];
        int p = pos[i];
        half8 pv = *((const half8*)pbuf + p);
        const float4* iv = (const float4*)(invb + (size_t)d * 8);
        float4 i0 = iv[0], i1 = iv[1];
        float4* op = (float4*)(attn_out + (size_t)i * 8);
        op[0] = make_float4((float)pv[0] * i0.x, (float)pv[1] * i0.y,
                            (float)pv[2] * i0.z, (float)pv[3] * i0.w);
        op[1] = make_float4((float)pv[4] * i1.x, (float)pv[5] * i1.y,
                            (float)pv[6] * i1.z, (float)pv[7] * i1.w);
    }
}

// ---------------- launch ----------------

extern "C" void kernel_launch(void* const* d_in, const int* in_sizes, int n_in,
                              void* d_out, int out_size, void* d_ws, size_t ws_size,
                              hipStream_t stream) {
    const float* x  = (const float*)d_in[0];
    const float* pi = (const float*)d_in[1];
    const float* vw = (const float*)d_in[2];
    const float* Wq = (const float*)d_in[3];
    const float* bq = (const float*)d_in[4];
    const float* Wk = (const float*)d_in[5];
    const float* bk = (const float*)d_in[6];
    const float* Wv = (const float*)d_in[7];
    const float* bv = (const float*)d_in[8];
    const int* src  = (const int*)d_in[9];
    const int* dst  = (const int*)d_in[10];

    int n = in_sizes[0] / 128;  // 100000
    int e = in_sizes[9];        // 1600000

    _Float16* xh = (_Float16*)d_ws;
    _Float16* qh = xh + (size_t)n * 128;
    _Float16* kh = qh + (size_t)n * 128;
    _Float16* vh = kh + (size_t)n * 128;
    _Float16* wt = vh + (size_t)n * 128;
    _Float16* pbuf = wt + 3 * 16384;
    float* invb  = (float*)(pbuf + (size_t)e * 8);
    int* counts  = (int*)(invb + (size_t)n * 8);
    int* cursor  = counts + n;
    int* row_ptr = cursor + n;
    int* bsum    = row_ptr + n + 1;
    int* pos     = bsum + 64;

    float* node_out = (float*)d_out;
    float* attn_out = node_out + (size_t)n * 128;
    // recs scratch (16B/edge = 25.6MB) lives in the 51.2MB attn output region:
    // written by fill_csr, consumed by edge_attn, overwritten by attn_norm.
    int4* recs = (int4*)attn_out;

    hipMemsetAsync(counts, 0, (size_t)n * sizeof(int), stream);

    int eb = (e + 255) / 256;
    hist_kernel<<<eb, 256, 0, stream>>>(dst, counts, e);

    int nb = (n + SCAN_CHUNK - 1) / SCAN_CHUNK;  // 49
    scan_block_sums<<<nb, 256, 0, stream>>>(counts, bsum, n);
    scan_wave<<<1, 64, 0, stream>>>(bsum, nb);
    scan_write<<<nb, 256, 0, stream>>>(counts, bsum, row_ptr, cursor, n, e);
    fill_csr<<<eb, 256, 0, stream>>>(dst, src, vw, cursor, recs, pos, e);

    int tot8 = (n * 128) / 8;
    convert_x<<<(tot8 + 255) / 256, 256, 0, stream>>>(x, xh, tot8);
    prep_w<<<3, 256, 0, stream>>>(Wq, Wk, Wv, wt);

    int gtiles = (n + 127) / 128;
    qkv_mfma<<<dim3(gtiles, 3), 256, 0, stream>>>(xh, wt, bq, bk, bv, qh, kh, vh, n);

    int gb = (n + 3) / 4;
    edge_attn<<<gb, 64, 0, stream>>>(qh, kh, vh, pi, row_ptr, recs,
                                     node_out, invb, pbuf, n);
    attn_norm<<<eb, 256, 0, stream>>>(pbuf, dst, pos, invb, attn_out, e);
}